// Round 1
// baseline (2472.837 us; speedup 1.0000x reference)
//
#include <hip/hip_runtime.h>
#include <stdint.h>

typedef float f32x4 __attribute__((ext_vector_type(4)));
typedef __bf16 bf16x8 __attribute__((ext_vector_type(8)));
typedef unsigned short u16x4 __attribute__((ext_vector_type(4)));
typedef unsigned short u16x8 __attribute__((ext_vector_type(8)));

#define B_ROWS 16384
#define IN_DIM 512
#define HID_DIM 1024
#define OUT_DIM 512
#define K_CAT 1536   // IN + HID

// ---------- helpers ----------

__device__ __forceinline__ unsigned short f2bf(float f) {
  unsigned u = __builtin_bit_cast(unsigned, f);
  unsigned r = u + 0x7fffu + ((u >> 16) & 1u);  // RNE
  return (unsigned short)(r >> 16);
}

__device__ __forceinline__ float sigmoidf_(float x) {
  return 1.f / (1.f + __expf(-x));
}
__device__ __forceinline__ float tanhf_(float x) {
  return 2.f / (1.f + __expf(-2.f * x)) - 1.f;
}

// async global->LDS, 16B per lane; LDS dest = wave-uniform base + lane*16
__device__ __forceinline__ void async16(const void* g, void* l) {
  const __attribute__((address_space(1))) unsigned int* gp =
      reinterpret_cast<const __attribute__((address_space(1))) unsigned int*>(
          reinterpret_cast<uintptr_t>(g));
  __attribute__((address_space(3))) unsigned int* lp =
      reinterpret_cast<__attribute__((address_space(3))) unsigned int*>(
          reinterpret_cast<uintptr_t>(l));
  __builtin_amdgcn_global_load_lds(gp, lp, 16, 0, 0);
}

// ---------- P1: cast x||h -> bf16 A[16384][1536], fc_w -> bf16 ----------
// grid: 12544 * 256 threads == 3,145,728 (A/8) + 65,536 (fcw/8) exactly.

__global__ void prep_cast_kernel(const float* __restrict__ x,
                                 const float* __restrict__ h,
                                 const float* __restrict__ fcw,
                                 unsigned short* __restrict__ A,
                                 unsigned short* __restrict__ fcw16) {
  int gid = blockIdx.x * 256 + threadIdx.x;
  const int NA = B_ROWS * K_CAT / 8;
  const float* src;
  unsigned short* dst;
  if (gid < NA) {
    int flat = gid * 8;
    int row = flat / K_CAT;
    int col = flat - row * K_CAT;
    src = (col < IN_DIM) ? (x + (size_t)row * IN_DIM + col)
                         : (h + (size_t)row * HID_DIM + (col - IN_DIM));
    dst = A + flat;
  } else {
    int j = (gid - NA) * 8;
    src = fcw + j;
    dst = fcw16 + j;
  }
  f32x4 v0 = *(const f32x4*)src;
  f32x4 v1 = *(const f32x4*)(src + 4);
  u16x8 o;
  o[0] = f2bf(v0[0]); o[1] = f2bf(v0[1]); o[2] = f2bf(v0[2]); o[3] = f2bf(v0[3]);
  o[4] = f2bf(v1[0]); o[5] = f2bf(v1[1]); o[6] = f2bf(v1[2]); o[7] = f2bf(v1[3]);
  *(u16x8*)dst = o;
}

// ---------- P2: pack Wt[g][n][k] = (k<512 ? W_g[k][n] : U_g[k-512][n]) bf16 ----------
// Tiled transpose. grid (32 n-tiles, 48 k-tiles, 4 gates), block 256.

__global__ void pack_w_kernel(const float* __restrict__ W0, const float* __restrict__ W1,
                              const float* __restrict__ W2, const float* __restrict__ W3,
                              const float* __restrict__ U0, const float* __restrict__ U1,
                              const float* __restrict__ U2, const float* __restrict__ U3,
                              unsigned short* __restrict__ Wt) {
  __shared__ float tile[32][33];
  int g = blockIdx.z;
  int n0 = blockIdx.x * 32;
  int k0 = blockIdx.y * 32;
  const float* Wg = g == 0 ? W0 : g == 1 ? W1 : g == 2 ? W2 : W3;
  const float* Ug = g == 0 ? U0 : g == 1 ? U1 : g == 2 ? U2 : U3;
  int tx = threadIdx.x & 31, ty = threadIdx.x >> 5;
#pragma unroll
  for (int i = 0; i < 4; ++i) {
    int ky = ty + i * 8;
    int k = k0 + ky;
    float v = (k < IN_DIM) ? Wg[(size_t)k * HID_DIM + n0 + tx]
                           : Ug[(size_t)(k - IN_DIM) * HID_DIM + n0 + tx];
    tile[ky][tx] = v;
  }
  __syncthreads();
#pragma unroll
  for (int i = 0; i < 4; ++i) {
    int ny = ty + i * 8;
    Wt[((size_t)g * HID_DIM + n0 + ny) * K_CAT + k0 + tx] = f2bf(tile[tx][ny]);
  }
}

// ---------- G1: fused gates GEMM + LSTM cell ----------
// Block = 256 threads (4 waves). Tile: 128 rows x 32 h-cols x 4 gates.
// Wave g computes gate g: acc[8][2] 16x16 MFMA tiles over K=1536.
// Staging per K-step: sA 128x32 bf16 (8KB) + sB[4] 32x32 bf16 (8KB) = 16 chunks
// of 1KB via global_load_lds width 16; wave w owns chunks 4w..4w+3.

__global__ __launch_bounds__(256, 2) void lstm_gates_kernel(
    const unsigned short* __restrict__ A,   // [16384][1536] bf16
    const unsigned short* __restrict__ Wt,  // [4][1024][1536] bf16
    const float* __restrict__ c_t,
    const float* __restrict__ b_i, const float* __restrict__ b_f,
    const float* __restrict__ b_o, const float* __restrict__ b_c,
    float* __restrict__ h_new, float* __restrict__ c_new,
    unsigned short* __restrict__ h_bf) {
  const int h0 = blockIdx.x * 32;
  const int m0 = blockIdx.y * 128;
  const int tid = threadIdx.x;
  const int wave = tid >> 6, lane = tid & 63;
  const int lane16 = lane & 15, quad = lane >> 4;

  __shared__ __align__(16) union {
    unsigned short stage[8192];  // [sA 128*32 | sB0..sB3 32*32 each] bf16
    float act[4 * 32 * 36];      // 4 gates x 32 rows x (32 cols, stride 36)
  } lds;

  const unsigned short* gbase[4];
  int goff[4];
  int ldsoff[4];
#pragma unroll
  for (int cc = 0; cc < 4; ++cc) {
    int chunk = wave * 4 + cc;
    ldsoff[cc] = chunk * 1024;  // bytes
    int rr = lane >> 2;
    int col = (lane & 3) * 8;
    if (chunk < 8) {  // A tile: row = chunk*16 + lane/4
      gbase[cc] = A;
      goff[cc] = (m0 + chunk * 16 + rr) * K_CAT + col;
    } else {          // B tiles: gate = (chunk-8)/2
      int bb = chunk - 8;
      gbase[cc] = Wt;
      goff[cc] = ((bb >> 1) * HID_DIM + h0 + (bb & 1) * 16 + rr) * K_CAT + col;
    }
  }

  f32x4 acc[8][2];
#pragma unroll
  for (int i = 0; i < 8; ++i)
#pragma unroll
    for (int j = 0; j < 2; ++j) {
      acc[i][j][0] = 0.f; acc[i][j][1] = 0.f; acc[i][j][2] = 0.f; acc[i][j][3] = 0.f;
    }

  const unsigned short* sA = lds.stage;
  const unsigned short* sBg = lds.stage + 4096 + wave * 1024;

  for (int kt = 0; kt < K_CAT; kt += 32) {
#pragma unroll
    for (int cc = 0; cc < 4; ++cc)
      async16(gbase[cc] + goff[cc] + kt, (char*)lds.stage + ldsoff[cc]);
    __syncthreads();  // drains vmcnt (global_load_lds) + barrier
    bf16x8 a[8], b[2];
#pragma unroll
    for (int mt = 0; mt < 8; ++mt)
      a[mt] = *(const bf16x8*)(sA + (mt * 16 + lane16) * 32 + quad * 8);
#pragma unroll
    for (int nt = 0; nt < 2; ++nt)
      b[nt] = *(const bf16x8*)(sBg + (nt * 16 + lane16) * 32 + quad * 8);
#pragma unroll
    for (int mt = 0; mt < 8; ++mt)
#pragma unroll
      for (int nt = 0; nt < 2; ++nt)
        acc[mt][nt] =
            __builtin_amdgcn_mfma_f32_16x16x32_bf16(a[mt], b[nt], acc[mt][nt], 0, 0, 0);
    __syncthreads();
  }

  // ---- epilogue: activations + cell update, chunked 32 rows at a time ----
  const float* bgp = (wave == 0) ? b_i : (wave == 1) ? b_f : (wave == 2) ? b_o : b_c;
  float bv[2];
#pragma unroll
  for (int nt = 0; nt < 2; ++nt) bv[nt] = bgp[h0 + nt * 16 + lane16];

  for (int chunk = 0; chunk < 4; ++chunk) {
#pragma unroll
    for (int mtl = 0; mtl < 2; ++mtl) {
      int mt = chunk * 2 + mtl;
#pragma unroll
      for (int nt = 0; nt < 2; ++nt) {
#pragma unroll
        for (int r = 0; r < 4; ++r) {
          int rowl = mtl * 16 + quad * 4 + r;  // 0..31 within chunk
          int col = nt * 16 + lane16;          // 0..31
          float v = acc[mt][nt][r] + bv[nt];
          float a = (wave < 3) ? sigmoidf_(v) : tanhf_(v);
          lds.act[(wave * 32 + rowl) * 36 + col] = a;
        }
      }
    }
    __syncthreads();
    {
      int rowl = tid >> 3;
      int col0 = (tid & 7) * 4;
      f32x4 iv = *(const f32x4*)&lds.act[(0 + rowl) * 36 + col0];
      f32x4 fv = *(const f32x4*)&lds.act[(32 + rowl) * 36 + col0];
      f32x4 ov = *(const f32x4*)&lds.act[(64 + rowl) * 36 + col0];
      f32x4 gv = *(const f32x4*)&lds.act[(96 + rowl) * 36 + col0];
      int grow = m0 + chunk * 32 + rowl;
      int gcol = h0 + col0;
      size_t off = (size_t)grow * HID_DIM + gcol;
      f32x4 cold = *(const f32x4*)(c_t + off);
      f32x4 cn, hn;
      u16x4 hb;
#pragma unroll
      for (int j = 0; j < 4; ++j) {
        float c2 = fv[j] * cold[j] + iv[j] * gv[j];
        float h2 = ov[j] * tanhf_(c2);
        cn[j] = c2;
        hn[j] = h2;
        hb[j] = f2bf(h2);
      }
      *(f32x4*)(c_new + off) = cn;
      *(f32x4*)(h_new + off) = hn;
      *(u16x4*)(h_bf + off) = hb;
    }
    __syncthreads();
  }
}

// ---------- G2: out = h_new_bf16 @ fc_w^T + fc_b ----------
// m97-style 128x128 bt-GEMM; fc_w [512][1024] is already B^T layout.

__global__ __launch_bounds__(256, 2) void fc_kernel(
    const unsigned short* __restrict__ A,   // [16384][1024] bf16
    const unsigned short* __restrict__ Bt,  // [512][1024] bf16
    const float* __restrict__ bias, float* __restrict__ out) {
  const int n0 = blockIdx.x * 128;
  const int m0 = blockIdx.y * 128;
  const int tid = threadIdx.x;
  const int wave = tid >> 6, lane = tid & 63;
  const int lane16 = lane & 15, quad = lane >> 4;
  const int wm = wave & 1, wn = wave >> 1;

  __shared__ __align__(16) unsigned short stage[8192];  // sA 128x32 | sB 128x32

  const unsigned short* gbase[4];
  int goff[4];
  int ldsoff[4];
#pragma unroll
  for (int cc = 0; cc < 4; ++cc) {
    int chunk = wave * 4 + cc;
    ldsoff[cc] = chunk * 1024;
    int rr = lane >> 2;
    int col = (lane & 3) * 8;
    if (chunk < 8) {
      gbase[cc] = A;
      goff[cc] = (m0 + chunk * 16 + rr) * HID_DIM + col;
    } else {
      gbase[cc] = Bt;
      goff[cc] = (n0 + (chunk - 8) * 16 + rr) * HID_DIM + col;
    }
  }

  f32x4 acc[4][4];
#pragma unroll
  for (int i = 0; i < 4; ++i)
#pragma unroll
    for (int j = 0; j < 4; ++j) {
      acc[i][j][0] = 0.f; acc[i][j][1] = 0.f; acc[i][j][2] = 0.f; acc[i][j][3] = 0.f;
    }

  const unsigned short* sA = stage;
  const unsigned short* sB = stage + 4096;

  for (int kt = 0; kt < HID_DIM; kt += 32) {
#pragma unroll
    for (int cc = 0; cc < 4; ++cc)
      async16(gbase[cc] + goff[cc] + kt, (char*)stage + ldsoff[cc]);
    __syncthreads();
    bf16x8 a[4], b[4];
#pragma unroll
    for (int mt = 0; mt < 4; ++mt)
      a[mt] = *(const bf16x8*)(sA + (wm * 64 + mt * 16 + lane16) * 32 + quad * 8);
#pragma unroll
    for (int nt = 0; nt < 4; ++nt)
      b[nt] = *(const bf16x8*)(sB + (wn * 64 + nt * 16 + lane16) * 32 + quad * 8);
#pragma unroll
    for (int mt = 0; mt < 4; ++mt)
#pragma unroll
      for (int nt = 0; nt < 4; ++nt)
        acc[mt][nt] =
            __builtin_amdgcn_mfma_f32_16x16x32_bf16(a[mt], b[nt], acc[mt][nt], 0, 0, 0);
    __syncthreads();
  }

#pragma unroll
  for (int nt = 0; nt < 4; ++nt) {
    int gcol = n0 + wn * 64 + nt * 16 + lane16;
    float bb = bias[gcol];
#pragma unroll
    for (int mt = 0; mt < 4; ++mt) {
#pragma unroll
      for (int r = 0; r < 4; ++r) {
        int grow = m0 + wm * 64 + mt * 16 + quad * 4 + r;
        out[(size_t)grow * OUT_DIM + gcol] = acc[mt][nt][r] + bb;
      }
    }
  }
}

// ---------- launch ----------

extern "C" void kernel_launch(void* const* d_in, const int* in_sizes, int n_in,
                              void* d_out, int out_size, void* d_ws, size_t ws_size,
                              hipStream_t stream) {
  const float* x = (const float*)d_in[0];
  const float* h = (const float*)d_in[1];
  const float* c = (const float*)d_in[2];
  const float* W0 = (const float*)d_in[3];
  const float* U0 = (const float*)d_in[4];
  const float* b0 = (const float*)d_in[5];
  const float* W1 = (const float*)d_in[6];
  const float* U1 = (const float*)d_in[7];
  const float* b1 = (const float*)d_in[8];
  const float* W2 = (const float*)d_in[9];
  const float* U2 = (const float*)d_in[10];
  const float* b2 = (const float*)d_in[11];
  const float* W3 = (const float*)d_in[12];
  const float* U3 = (const float*)d_in[13];
  const float* b3 = (const float*)d_in[14];
  const float* fcw = (const float*)d_in[15];
  const float* fcb = (const float*)d_in[16];

  float* out = (float*)d_out;                          // [16384][512]
  float* h_new = out + (size_t)B_ROWS * OUT_DIM;       // [16384][1024]
  float* c_new = h_new + (size_t)B_ROWS * HID_DIM;     // [16384][1024]

  unsigned short* wsA = (unsigned short*)d_ws;                 // 16384*1536
  unsigned short* wsWt = wsA + (size_t)B_ROWS * K_CAT;         // 4*1024*1536
  unsigned short* wsFc = wsWt + (size_t)4 * HID_DIM * K_CAT;   // 512*1024
  unsigned short* wsH = wsFc + (size_t)OUT_DIM * HID_DIM;      // 16384*1024
  // total ws: ~93 MB

  prep_cast_kernel<<<dim3(12544), dim3(256), 0, stream>>>(x, h, fcw, wsA, wsFc);
  pack_w_kernel<<<dim3(32, 48, 4), dim3(256), 0, stream>>>(W0, W1, W2, W3, U0, U1,
                                                           U2, U3, wsWt);
  lstm_gates_kernel<<<dim3(32, 128), dim3(256), 0, stream>>>(
      wsA, wsWt, c, b0, b1, b2, b3, h_new, c_new, wsH);
  fc_kernel<<<dim3(4, 128), dim3(256), 0, stream>>>(wsH, wsFc, fcb, out);
}

// Round 2
// 598.972 us; speedup vs baseline: 4.1285x; 4.1285x over previous
//
#include <hip/hip_runtime.h>
#include <stdint.h>

typedef float f32x4 __attribute__((ext_vector_type(4)));
typedef __bf16 bf16x8 __attribute__((ext_vector_type(8)));
typedef unsigned short u16x4 __attribute__((ext_vector_type(4)));
typedef unsigned short u16x8 __attribute__((ext_vector_type(8)));

#define B_ROWS 16384
#define IN_DIM 512
#define HID_DIM 1024
#define OUT_DIM 512
#define K_CAT 1536   // IN + HID

// ---------- helpers ----------

__device__ __forceinline__ unsigned short f2bf(float f) {
  unsigned u = __builtin_bit_cast(unsigned, f);
  unsigned r = u + 0x7fffu + ((u >> 16) & 1u);  // RNE
  return (unsigned short)(r >> 16);
}

__device__ __forceinline__ float sigmoidf_(float x) {
  return 1.f / (1.f + __expf(-x));
}
__device__ __forceinline__ float tanhf_(float x) {
  return 2.f / (1.f + __expf(-2.f * x)) - 1.f;
}

// async global->LDS, 16B per lane; LDS dest = wave-uniform base + lane*16
__device__ __forceinline__ void async16(const void* g, void* l) {
  const __attribute__((address_space(1))) unsigned int* gp =
      reinterpret_cast<const __attribute__((address_space(1))) unsigned int*>(
          reinterpret_cast<uintptr_t>(g));
  __attribute__((address_space(3))) unsigned int* lp =
      reinterpret_cast<__attribute__((address_space(3))) unsigned int*>(
          reinterpret_cast<uintptr_t>(l));
  __builtin_amdgcn_global_load_lds(gp, lp, 16, 0, 0);
}

// ---------- P1: cast x||h -> bf16 A[16384][1536], fc_w -> bf16 ----------
// grid: 12544 * 256 threads == 3,145,728 (A/8) + 65,536 (fcw/8) exactly.

__global__ void prep_cast_kernel(const float* __restrict__ x,
                                 const float* __restrict__ h,
                                 const float* __restrict__ fcw,
                                 unsigned short* __restrict__ A,
                                 unsigned short* __restrict__ fcw16) {
  int gid = blockIdx.x * 256 + threadIdx.x;
  const int NA = B_ROWS * K_CAT / 8;
  const float* src;
  unsigned short* dst;
  if (gid < NA) {
    int flat = gid * 8;
    int row = flat / K_CAT;
    int col = flat - row * K_CAT;
    src = (col < IN_DIM) ? (x + (size_t)row * IN_DIM + col)
                         : (h + (size_t)row * HID_DIM + (col - IN_DIM));
    dst = A + flat;
  } else {
    int j = (gid - NA) * 8;
    src = fcw + j;
    dst = fcw16 + j;
  }
  f32x4 v0 = *(const f32x4*)src;
  f32x4 v1 = *(const f32x4*)(src + 4);
  u16x8 o;
  o[0] = f2bf(v0[0]); o[1] = f2bf(v0[1]); o[2] = f2bf(v0[2]); o[3] = f2bf(v0[3]);
  o[4] = f2bf(v1[0]); o[5] = f2bf(v1[1]); o[6] = f2bf(v1[2]); o[7] = f2bf(v1[3]);
  *(u16x8*)dst = o;
}

// ---------- P2: pack Wt[g][n][k] = (k<512 ? W_g[k][n] : U_g[k-512][n]) bf16 ----------
// Tiled transpose. grid (32 n-tiles, 48 k-tiles, 4 gates), block 256.

__global__ void pack_w_kernel(const float* __restrict__ W0, const float* __restrict__ W1,
                              const float* __restrict__ W2, const float* __restrict__ W3,
                              const float* __restrict__ U0, const float* __restrict__ U1,
                              const float* __restrict__ U2, const float* __restrict__ U3,
                              unsigned short* __restrict__ Wt) {
  __shared__ float tile[32][33];
  int g = blockIdx.z;
  int n0 = blockIdx.x * 32;
  int k0 = blockIdx.y * 32;
  const float* Wg = g == 0 ? W0 : g == 1 ? W1 : g == 2 ? W2 : W3;
  const float* Ug = g == 0 ? U0 : g == 1 ? U1 : g == 2 ? U2 : U3;
  int tx = threadIdx.x & 31, ty = threadIdx.x >> 5;
#pragma unroll
  for (int i = 0; i < 4; ++i) {
    int ky = ty + i * 8;
    int k = k0 + ky;
    float v = (k < IN_DIM) ? Wg[(size_t)k * HID_DIM + n0 + tx]
                           : Ug[(size_t)(k - IN_DIM) * HID_DIM + n0 + tx];
    tile[ky][tx] = v;
  }
  __syncthreads();
#pragma unroll
  for (int i = 0; i < 4; ++i) {
    int ny = ty + i * 8;
    Wt[((size_t)g * HID_DIM + n0 + ny) * K_CAT + k0 + tx] = f2bf(tile[tx][ny]);
  }
}

// ---------- G1: fused gates GEMM + LSTM cell ----------
// Block = 256 threads (4 waves). Tile: 128 rows x 32 h-cols x 4 gates.
// Wave g computes gate g: acc[8][2] 16x16 MFMA tiles over K=1536.
// Staging per K-step: sA 128x32 bf16 (8KB) + sB[4] 32x32 bf16 (8KB) = 16 chunks
// of 1KB via global_load_lds width 16; wave w owns chunks 4w..4w+3.
// NOTE: epilogue chunk loop MUST be fully unrolled — dynamic indexing into
// acc[] demotes the accumulator array to scratch (11.6 GB spill traffic, R1).

__global__ __launch_bounds__(256, 2) void lstm_gates_kernel(
    const unsigned short* __restrict__ A,   // [16384][1536] bf16
    const unsigned short* __restrict__ Wt,  // [4][1024][1536] bf16
    const float* __restrict__ c_t,
    const float* __restrict__ b_i, const float* __restrict__ b_f,
    const float* __restrict__ b_o, const float* __restrict__ b_c,
    float* __restrict__ h_new, float* __restrict__ c_new,
    unsigned short* __restrict__ h_bf) {
  const int h0 = blockIdx.x * 32;
  const int m0 = blockIdx.y * 128;
  const int tid = threadIdx.x;
  const int wave = tid >> 6, lane = tid & 63;
  const int lane16 = lane & 15, quad = lane >> 4;

  __shared__ __align__(16) union {
    unsigned short stage[8192];  // [sA 128*32 | sB0..sB3 32*32 each] bf16
    float act[4 * 32 * 36];      // 4 gates x 32 rows x (32 cols, stride 36)
  } lds;

  const unsigned short* gbase[4];
  int goff[4];
  int ldsoff[4];
#pragma unroll
  for (int cc = 0; cc < 4; ++cc) {
    int chunk = wave * 4 + cc;
    ldsoff[cc] = chunk * 1024;  // bytes
    int rr = lane >> 2;
    int col = (lane & 3) * 8;
    if (chunk < 8) {  // A tile: row = chunk*16 + lane/4
      gbase[cc] = A;
      goff[cc] = (m0 + chunk * 16 + rr) * K_CAT + col;
    } else {          // B tiles: gate = (chunk-8)/2
      int bb = chunk - 8;
      gbase[cc] = Wt;
      goff[cc] = ((bb >> 1) * HID_DIM + h0 + (bb & 1) * 16 + rr) * K_CAT + col;
    }
  }

  f32x4 acc[8][2];
#pragma unroll
  for (int i = 0; i < 8; ++i)
#pragma unroll
    for (int j = 0; j < 2; ++j) {
      acc[i][j][0] = 0.f; acc[i][j][1] = 0.f; acc[i][j][2] = 0.f; acc[i][j][3] = 0.f;
    }

  const unsigned short* sA = lds.stage;
  const unsigned short* sBg = lds.stage + 4096 + wave * 1024;

  for (int kt = 0; kt < K_CAT; kt += 32) {
#pragma unroll
    for (int cc = 0; cc < 4; ++cc)
      async16(gbase[cc] + goff[cc] + kt, (char*)lds.stage + ldsoff[cc]);
    __syncthreads();  // drains vmcnt (global_load_lds) + barrier
    bf16x8 a[8], b[2];
#pragma unroll
    for (int mt = 0; mt < 8; ++mt)
      a[mt] = *(const bf16x8*)(sA + (mt * 16 + lane16) * 32 + quad * 8);
#pragma unroll
    for (int nt = 0; nt < 2; ++nt)
      b[nt] = *(const bf16x8*)(sBg + (nt * 16 + lane16) * 32 + quad * 8);
#pragma unroll
    for (int mt = 0; mt < 8; ++mt)
#pragma unroll
      for (int nt = 0; nt < 2; ++nt)
        acc[mt][nt] =
            __builtin_amdgcn_mfma_f32_16x16x32_bf16(a[mt], b[nt], acc[mt][nt], 0, 0, 0);
    __syncthreads();
  }

  // ---- epilogue: activations + cell update, chunked 32 rows at a time ----
  const float* bgp = (wave == 0) ? b_i : (wave == 1) ? b_f : (wave == 2) ? b_o : b_c;
  float bv[2];
#pragma unroll
  for (int nt = 0; nt < 2; ++nt) bv[nt] = bgp[h0 + nt * 16 + lane16];

#pragma unroll
  for (int chunk = 0; chunk < 4; ++chunk) {
#pragma unroll
    for (int mtl = 0; mtl < 2; ++mtl) {
      const int mt = chunk * 2 + mtl;
#pragma unroll
      for (int nt = 0; nt < 2; ++nt) {
#pragma unroll
        for (int r = 0; r < 4; ++r) {
          int rowl = mtl * 16 + quad * 4 + r;  // 0..31 within chunk
          int col = nt * 16 + lane16;          // 0..31
          float v = acc[mt][nt][r] + bv[nt];
          float a = (wave < 3) ? sigmoidf_(v) : tanhf_(v);
          lds.act[(wave * 32 + rowl) * 36 + col] = a;
        }
      }
    }
    __syncthreads();
    {
      int rowl = tid >> 3;
      int col0 = (tid & 7) * 4;
      f32x4 iv = *(const f32x4*)&lds.act[(0 + rowl) * 36 + col0];
      f32x4 fv = *(const f32x4*)&lds.act[(32 + rowl) * 36 + col0];
      f32x4 ov = *(const f32x4*)&lds.act[(64 + rowl) * 36 + col0];
      f32x4 gv = *(const f32x4*)&lds.act[(96 + rowl) * 36 + col0];
      int grow = m0 + chunk * 32 + rowl;
      int gcol = h0 + col0;
      size_t off = (size_t)grow * HID_DIM + gcol;
      f32x4 cold = *(const f32x4*)(c_t + off);
      f32x4 cn, hn;
      u16x4 hb;
#pragma unroll
      for (int j = 0; j < 4; ++j) {
        float c2 = fv[j] * cold[j] + iv[j] * gv[j];
        float h2 = ov[j] * tanhf_(c2);
        cn[j] = c2;
        hn[j] = h2;
        hb[j] = f2bf(h2);
      }
      *(f32x4*)(c_new + off) = cn;
      *(f32x4*)(h_new + off) = hn;
      *(u16x4*)(h_bf + off) = hb;
    }
    __syncthreads();
  }
}

// ---------- G2: out = h_new_bf16 @ fc_w^T + fc_b ----------
// m97-style 128x128 bt-GEMM; fc_w [512][1024] is already B^T layout.

__global__ __launch_bounds__(256, 2) void fc_kernel(
    const unsigned short* __restrict__ A,   // [16384][1024] bf16
    const unsigned short* __restrict__ Bt,  // [512][1024] bf16
    const float* __restrict__ bias, float* __restrict__ out) {
  const int n0 = blockIdx.x * 128;
  const int m0 = blockIdx.y * 128;
  const int tid = threadIdx.x;
  const int wave = tid >> 6, lane = tid & 63;
  const int lane16 = lane & 15, quad = lane >> 4;
  const int wm = wave & 1, wn = wave >> 1;

  __shared__ __align__(16) unsigned short stage[8192];  // sA 128x32 | sB 128x32

  const unsigned short* gbase[4];
  int goff[4];
  int ldsoff[4];
#pragma unroll
  for (int cc = 0; cc < 4; ++cc) {
    int chunk = wave * 4 + cc;
    ldsoff[cc] = chunk * 1024;
    int rr = lane >> 2;
    int col = (lane & 3) * 8;
    if (chunk < 8) {
      gbase[cc] = A;
      goff[cc] = (m0 + chunk * 16 + rr) * HID_DIM + col;
    } else {
      gbase[cc] = Bt;
      goff[cc] = (n0 + (chunk - 8) * 16 + rr) * HID_DIM + col;
    }
  }

  f32x4 acc[4][4];
#pragma unroll
  for (int i = 0; i < 4; ++i)
#pragma unroll
    for (int j = 0; j < 4; ++j) {
      acc[i][j][0] = 0.f; acc[i][j][1] = 0.f; acc[i][j][2] = 0.f; acc[i][j][3] = 0.f;
    }

  const unsigned short* sA = stage;
  const unsigned short* sB = stage + 4096;

  for (int kt = 0; kt < HID_DIM; kt += 32) {
#pragma unroll
    for (int cc = 0; cc < 4; ++cc)
      async16(gbase[cc] + goff[cc] + kt, (char*)stage + ldsoff[cc]);
    __syncthreads();
    bf16x8 a[4], b[4];
#pragma unroll
    for (int mt = 0; mt < 4; ++mt)
      a[mt] = *(const bf16x8*)(sA + (wm * 64 + mt * 16 + lane16) * 32 + quad * 8);
#pragma unroll
    for (int nt = 0; nt < 4; ++nt)
      b[nt] = *(const bf16x8*)(sB + (wn * 64 + nt * 16 + lane16) * 32 + quad * 8);
#pragma unroll
    for (int mt = 0; mt < 4; ++mt)
#pragma unroll
      for (int nt = 0; nt < 4; ++nt)
        acc[mt][nt] =
            __builtin_amdgcn_mfma_f32_16x16x32_bf16(a[mt], b[nt], acc[mt][nt], 0, 0, 0);
    __syncthreads();
  }

#pragma unroll
  for (int nt = 0; nt < 4; ++nt) {
    int gcol = n0 + wn * 64 + nt * 16 + lane16;
    float bb = bias[gcol];
#pragma unroll
    for (int mt = 0; mt < 4; ++mt) {
#pragma unroll
      for (int r = 0; r < 4; ++r) {
        int grow = m0 + wm * 64 + mt * 16 + quad * 4 + r;
        out[(size_t)grow * OUT_DIM + gcol] = acc[mt][nt][r] + bb;
      }
    }
  }
}

// ---------- launch ----------

extern "C" void kernel_launch(void* const* d_in, const int* in_sizes, int n_in,
                              void* d_out, int out_size, void* d_ws, size_t ws_size,
                              hipStream_t stream) {
  const float* x = (const float*)d_in[0];
  const float* h = (const float*)d_in[1];
  const float* c = (const float*)d_in[2];
  const float* W0 = (const float*)d_in[3];
  const float* U0 = (const float*)d_in[4];
  const float* b0 = (const float*)d_in[5];
  const float* W1 = (const float*)d_in[6];
  const float* U1 = (const float*)d_in[7];
  const float* b1 = (const float*)d_in[8];
  const float* W2 = (const float*)d_in[9];
  const float* U2 = (const float*)d_in[10];
  const float* b2 = (const float*)d_in[11];
  const float* W3 = (const float*)d_in[12];
  const float* U3 = (const float*)d_in[13];
  const float* b3 = (const float*)d_in[14];
  const float* fcw = (const float*)d_in[15];
  const float* fcb = (const float*)d_in[16];

  float* out = (float*)d_out;                          // [16384][512]
  float* h_new = out + (size_t)B_ROWS * OUT_DIM;       // [16384][1024]
  float* c_new = h_new + (size_t)B_ROWS * HID_DIM;     // [16384][1024]

  unsigned short* wsA = (unsigned short*)d_ws;                 // 16384*1536
  unsigned short* wsWt = wsA + (size_t)B_ROWS * K_CAT;         // 4*1024*1536
  unsigned short* wsFc = wsWt + (size_t)4 * HID_DIM * K_CAT;   // 512*1024
  unsigned short* wsH = wsFc + (size_t)OUT_DIM * HID_DIM;      // 16384*1024
  // total ws: ~93 MB

  prep_cast_kernel<<<dim3(12544), dim3(256), 0, stream>>>(x, h, fcw, wsA, wsFc);
  pack_w_kernel<<<dim3(32, 48, 4), dim3(256), 0, stream>>>(W0, W1, W2, W3, U0, U1,
                                                           U2, U3, wsWt);
  lstm_gates_kernel<<<dim3(32, 128), dim3(256), 0, stream>>>(
      wsA, wsWt, c, b0, b1, b2, b3, h_new, c_new, wsH);
  fc_kernel<<<dim3(4, 128), dim3(256), 0, stream>>>(wsH, wsFc, fcb, out);
}

// Round 3
// 585.417 us; speedup vs baseline: 4.2241x; 1.0232x over previous
//
#include <hip/hip_runtime.h>
#include <stdint.h>

typedef float f32x4 __attribute__((ext_vector_type(4)));
typedef __bf16 bf16x8 __attribute__((ext_vector_type(8)));
typedef unsigned short u16x4 __attribute__((ext_vector_type(4)));
typedef unsigned short u16x8 __attribute__((ext_vector_type(8)));

#define B_ROWS 16384
#define IN_DIM 512
#define HID_DIM 1024
#define OUT_DIM 512
#define K_CAT 1536   // IN + HID

// ---------- helpers ----------

__device__ __forceinline__ unsigned short f2bf(float f) {
  unsigned u = __builtin_bit_cast(unsigned, f);
  unsigned r = u + 0x7fffu + ((u >> 16) & 1u);  // RNE
  return (unsigned short)(r >> 16);
}

__device__ __forceinline__ float sigmoidf_(float x) {
  return 1.f / (1.f + __expf(-x));
}
__device__ __forceinline__ float tanhf_(float x) {
  return 2.f / (1.f + __expf(-2.f * x)) - 1.f;
}

// async global->LDS, 16B per lane; LDS dest = wave-uniform base + lane*16
__device__ __forceinline__ void async16(const void* g, void* l) {
  const __attribute__((address_space(1))) unsigned int* gp =
      reinterpret_cast<const __attribute__((address_space(1))) unsigned int*>(
          reinterpret_cast<uintptr_t>(g));
  __attribute__((address_space(3))) unsigned int* lp =
      reinterpret_cast<__attribute__((address_space(3))) unsigned int*>(
          reinterpret_cast<uintptr_t>(l));
  __builtin_amdgcn_global_load_lds(gp, lp, 16, 0, 0);
}

// ---------- P1: cast x||h -> bf16 A[16384][1536], fc_w -> bf16 ----------
// grid: 12544 * 256 threads == 3,145,728 (A/8) + 65,536 (fcw/8) exactly.

__global__ void prep_cast_kernel(const float* __restrict__ x,
                                 const float* __restrict__ h,
                                 const float* __restrict__ fcw,
                                 unsigned short* __restrict__ A,
                                 unsigned short* __restrict__ fcw16) {
  int gid = blockIdx.x * 256 + threadIdx.x;
  const int NA = B_ROWS * K_CAT / 8;
  const float* src;
  unsigned short* dst;
  if (gid < NA) {
    int flat = gid * 8;
    int row = flat / K_CAT;
    int col = flat - row * K_CAT;
    src = (col < IN_DIM) ? (x + (size_t)row * IN_DIM + col)
                         : (h + (size_t)row * HID_DIM + (col - IN_DIM));
    dst = A + flat;
  } else {
    int j = (gid - NA) * 8;
    src = fcw + j;
    dst = fcw16 + j;
  }
  f32x4 v0 = *(const f32x4*)src;
  f32x4 v1 = *(const f32x4*)(src + 4);
  u16x8 o;
  o[0] = f2bf(v0[0]); o[1] = f2bf(v0[1]); o[2] = f2bf(v0[2]); o[3] = f2bf(v0[3]);
  o[4] = f2bf(v1[0]); o[5] = f2bf(v1[1]); o[6] = f2bf(v1[2]); o[7] = f2bf(v1[3]);
  *(u16x8*)dst = o;
}

// ---------- P2: pack Wt[g][n][k] = (k<512 ? W_g[k][n] : U_g[k-512][n]) bf16 ----------
// Tiled transpose. grid (32 n-tiles, 48 k-tiles, 4 gates), block 256.

__global__ void pack_w_kernel(const float* __restrict__ W0, const float* __restrict__ W1,
                              const float* __restrict__ W2, const float* __restrict__ W3,
                              const float* __restrict__ U0, const float* __restrict__ U1,
                              const float* __restrict__ U2, const float* __restrict__ U3,
                              unsigned short* __restrict__ Wt) {
  __shared__ float tile[32][33];
  int g = blockIdx.z;
  int n0 = blockIdx.x * 32;
  int k0 = blockIdx.y * 32;
  const float* Wg = g == 0 ? W0 : g == 1 ? W1 : g == 2 ? W2 : W3;
  const float* Ug = g == 0 ? U0 : g == 1 ? U1 : g == 2 ? U2 : U3;
  int tx = threadIdx.x & 31, ty = threadIdx.x >> 5;
#pragma unroll
  for (int i = 0; i < 4; ++i) {
    int ky = ty + i * 8;
    int k = k0 + ky;
    float v = (k < IN_DIM) ? Wg[(size_t)k * HID_DIM + n0 + tx]
                           : Ug[(size_t)(k - IN_DIM) * HID_DIM + n0 + tx];
    tile[ky][tx] = v;
  }
  __syncthreads();
#pragma unroll
  for (int i = 0; i < 4; ++i) {
    int ny = ty + i * 8;
    Wt[((size_t)g * HID_DIM + n0 + ny) * K_CAT + k0 + tx] = f2bf(tile[tx][ny]);
  }
}

// ---------- G1: fused gates GEMM + LSTM cell ----------
// Block = 256 threads (4 waves). Tile: 128 rows x 64 h-cols x 4 gates.
// Wave g computes gate g: acc[8][4] 16x16 MFMA tiles over K=1536.
// Staging per K-step: sA 128x32 bf16 (8KB) + sB 4x(64x32) bf16 (16KB) = 24
// chunks of 1KB via global_load_lds width 16; wave w owns chunks 6w..6w+5.
// NOTE: all acc[] indices must be compile-time constants — dynamic indexing
// demotes the accumulator to scratch (11.6 GB spill traffic, R1).

__global__ __launch_bounds__(256, 2) void lstm_gates_kernel(
    const unsigned short* __restrict__ A,   // [16384][1536] bf16
    const unsigned short* __restrict__ Wt,  // [4][1024][1536] bf16
    const float* __restrict__ c_t,
    const float* __restrict__ b_i, const float* __restrict__ b_f,
    const float* __restrict__ b_o, const float* __restrict__ b_c,
    float* __restrict__ h_new, float* __restrict__ c_new,
    unsigned short* __restrict__ h_bf) {
  const int m0 = blockIdx.x * 128;  // x = m so consecutive blocks share Wt slice
  const int h0 = blockIdx.y * 64;
  const int tid = threadIdx.x;
  const int wave = tid >> 6, lane = tid & 63;
  const int lane16 = lane & 15, quad = lane >> 4;

  __shared__ __align__(16) union {
    unsigned short stage[12288];  // [sA 128*32 | sB: gate g at 4096+g*2048 elems]
    float act[4 * 32 * 68];       // 4 gates x 32 rows x (64 cols, stride 68)
  } lds;

  // staging pointers: 6 chunks of 1KB per wave, advanced by 32 elems per k-step
  const unsigned short* gp[6];
  int ldsoff[6];
#pragma unroll
  for (int cc = 0; cc < 6; ++cc) {
    int chunk = wave * 6 + cc;
    ldsoff[cc] = chunk * 1024;  // bytes
    int rr = lane >> 2;
    int col = (lane & 3) * 8;
    if (chunk < 8) {  // A tile rows: chunk*16 + lane/4
      gp[cc] = A + (size_t)(m0 + chunk * 16 + rr) * K_CAT + col;
    } else {          // B tiles: gate = (chunk-8)>>2, nsub = (chunk-8)&3
      int bb = chunk - 8;
      gp[cc] = Wt + (size_t)((bb >> 2) * HID_DIM + h0 + (bb & 3) * 16 + rr) * K_CAT + col;
    }
  }

  f32x4 acc[8][4];
#pragma unroll
  for (int i = 0; i < 8; ++i)
#pragma unroll
    for (int j = 0; j < 4; ++j) {
      acc[i][j][0] = 0.f; acc[i][j][1] = 0.f; acc[i][j][2] = 0.f; acc[i][j][3] = 0.f;
    }

  const unsigned short* sA = lds.stage;
  const unsigned short* sBg = lds.stage + 4096 + wave * 2048;

  for (int kt = 0; kt < K_CAT; kt += 32) {
#pragma unroll
    for (int cc = 0; cc < 6; ++cc) {
      async16(gp[cc], (char*)lds.stage + ldsoff[cc]);
      gp[cc] += 32;
    }
    __syncthreads();  // drains vmcnt (global_load_lds) + barrier
    bf16x8 a[8], b[4];
#pragma unroll
    for (int mt = 0; mt < 8; ++mt)
      a[mt] = *(const bf16x8*)(sA + (mt * 16 + lane16) * 32 + quad * 8);
#pragma unroll
    for (int nt = 0; nt < 4; ++nt)
      b[nt] = *(const bf16x8*)(sBg + (nt * 16 + lane16) * 32 + quad * 8);
#pragma unroll
    for (int mt = 0; mt < 8; ++mt)
#pragma unroll
      for (int nt = 0; nt < 4; ++nt)
        acc[mt][nt] =
            __builtin_amdgcn_mfma_f32_16x16x32_bf16(a[mt], b[nt], acc[mt][nt], 0, 0, 0);
    __syncthreads();
  }

  // ---- epilogue: activations + cell update, chunked 32 rows at a time ----
  const float* bgp = (wave == 0) ? b_i : (wave == 1) ? b_f : (wave == 2) ? b_o : b_c;
  float bv[4];
#pragma unroll
  for (int nt = 0; nt < 4; ++nt) bv[nt] = bgp[h0 + nt * 16 + lane16];

#pragma unroll
  for (int chunk = 0; chunk < 4; ++chunk) {
#pragma unroll
    for (int mtl = 0; mtl < 2; ++mtl) {
      const int mt = chunk * 2 + mtl;
#pragma unroll
      for (int nt = 0; nt < 4; ++nt) {
#pragma unroll
        for (int r = 0; r < 4; ++r) {
          int rowl = mtl * 16 + quad * 4 + r;  // 0..31 within chunk
          int col = nt * 16 + lane16;          // 0..63
          float v = acc[mt][nt][r] + bv[nt];
          float a = (wave < 3) ? sigmoidf_(v) : tanhf_(v);
          lds.act[(wave * 32 + rowl) * 68 + col] = a;
        }
      }
    }
    __syncthreads();
    {
      int rowl = tid >> 3;          // 0..31
      int col0 = (tid & 7) * 8;     // 0..56
      int grow = m0 + chunk * 32 + rowl;
      size_t off = (size_t)grow * HID_DIM + h0 + col0;
      u16x8 hb;
#pragma unroll
      for (int half = 0; half < 2; ++half) {
        int c4 = col0 + half * 4;
        f32x4 iv = *(const f32x4*)&lds.act[(0  + rowl) * 68 + c4];
        f32x4 fv = *(const f32x4*)&lds.act[(32 + rowl) * 68 + c4];
        f32x4 ov = *(const f32x4*)&lds.act[(64 + rowl) * 68 + c4];
        f32x4 gv = *(const f32x4*)&lds.act[(96 + rowl) * 68 + c4];
        f32x4 cold = *(const f32x4*)(c_t + off + half * 4);
        f32x4 cn, hn;
#pragma unroll
        for (int j = 0; j < 4; ++j) {
          float c2 = fv[j] * cold[j] + iv[j] * gv[j];
          float h2 = ov[j] * tanhf_(c2);
          cn[j] = c2;
          hn[j] = h2;
          hb[half * 4 + j] = f2bf(h2);
        }
        *(f32x4*)(c_new + off + half * 4) = cn;
        *(f32x4*)(h_new + off + half * 4) = hn;
      }
      *(u16x8*)(h_bf + off) = hb;
    }
    __syncthreads();
  }
}

// ---------- G2: out = h_new_bf16 @ fc_w^T + fc_b ----------
// m97-style 128x128 bt-GEMM; fc_w [512][1024] is already B^T layout.

__global__ __launch_bounds__(256, 2) void fc_kernel(
    const unsigned short* __restrict__ A,   // [16384][1024] bf16
    const unsigned short* __restrict__ Bt,  // [512][1024] bf16
    const float* __restrict__ bias, float* __restrict__ out) {
  const int m0 = blockIdx.x * 128;  // x = m: consecutive blocks share Bt slice
  const int n0 = blockIdx.y * 128;
  const int tid = threadIdx.x;
  const int wave = tid >> 6, lane = tid & 63;
  const int lane16 = lane & 15, quad = lane >> 4;
  const int wm = wave & 1, wn = wave >> 1;

  __shared__ __align__(16) unsigned short stage[8192];  // sA 128x32 | sB 128x32

  const unsigned short* gp[4];
  int ldsoff[4];
#pragma unroll
  for (int cc = 0; cc < 4; ++cc) {
    int chunk = wave * 4 + cc;
    ldsoff[cc] = chunk * 1024;
    int rr = lane >> 2;
    int col = (lane & 3) * 8;
    if (chunk < 8) {
      gp[cc] = A + (size_t)(m0 + chunk * 16 + rr) * HID_DIM + col;
    } else {
      gp[cc] = Bt + (size_t)(n0 + (chunk - 8) * 16 + rr) * HID_DIM + col;
    }
  }

  f32x4 acc[4][4];
#pragma unroll
  for (int i = 0; i < 4; ++i)
#pragma unroll
    for (int j = 0; j < 4; ++j) {
      acc[i][j][0] = 0.f; acc[i][j][1] = 0.f; acc[i][j][2] = 0.f; acc[i][j][3] = 0.f;
    }

  const unsigned short* sA = stage;
  const unsigned short* sB = stage + 4096;

  for (int kt = 0; kt < HID_DIM; kt += 32) {
#pragma unroll
    for (int cc = 0; cc < 4; ++cc) {
      async16(gp[cc], (char*)stage + ldsoff[cc]);
      gp[cc] += 32;
    }
    __syncthreads();
    bf16x8 a[4], b[4];
#pragma unroll
    for (int mt = 0; mt < 4; ++mt)
      a[mt] = *(const bf16x8*)(sA + (wm * 64 + mt * 16 + lane16) * 32 + quad * 8);
#pragma unroll
    for (int nt = 0; nt < 4; ++nt)
      b[nt] = *(const bf16x8*)(sB + (wn * 64 + nt * 16 + lane16) * 32 + quad * 8);
#pragma unroll
    for (int mt = 0; mt < 4; ++mt)
#pragma unroll
      for (int nt = 0; nt < 4; ++nt)
        acc[mt][nt] =
            __builtin_amdgcn_mfma_f32_16x16x32_bf16(a[mt], b[nt], acc[mt][nt], 0, 0, 0);
    __syncthreads();
  }

#pragma unroll
  for (int nt = 0; nt < 4; ++nt) {
    int gcol = n0 + wn * 64 + nt * 16 + lane16;
    float bb = bias[gcol];
#pragma unroll
    for (int mt = 0; mt < 4; ++mt) {
#pragma unroll
      for (int r = 0; r < 4; ++r) {
        int grow = m0 + wm * 64 + mt * 16 + quad * 4 + r;
        out[(size_t)grow * OUT_DIM + gcol] = acc[mt][nt][r] + bb;
      }
    }
  }
}

// ---------- launch ----------

extern "C" void kernel_launch(void* const* d_in, const int* in_sizes, int n_in,
                              void* d_out, int out_size, void* d_ws, size_t ws_size,
                              hipStream_t stream) {
  const float* x = (const float*)d_in[0];
  const float* h = (const float*)d_in[1];
  const float* c = (const float*)d_in[2];
  const float* W0 = (const float*)d_in[3];
  const float* U0 = (const float*)d_in[4];
  const float* b0 = (const float*)d_in[5];
  const float* W1 = (const float*)d_in[6];
  const float* U1 = (const float*)d_in[7];
  const float* b1 = (const float*)d_in[8];
  const float* W2 = (const float*)d_in[9];
  const float* U2 = (const float*)d_in[10];
  const float* b2 = (const float*)d_in[11];
  const float* W3 = (const float*)d_in[12];
  const float* U3 = (const float*)d_in[13];
  const float* b3 = (const float*)d_in[14];
  const float* fcw = (const float*)d_in[15];
  const float* fcb = (const float*)d_in[16];

  float* out = (float*)d_out;                          // [16384][512]
  float* h_new = out + (size_t)B_ROWS * OUT_DIM;       // [16384][1024]
  float* c_new = h_new + (size_t)B_ROWS * HID_DIM;     // [16384][1024]

  unsigned short* wsA = (unsigned short*)d_ws;                 // 16384*1536
  unsigned short* wsWt = wsA + (size_t)B_ROWS * K_CAT;         // 4*1024*1536
  unsigned short* wsFc = wsWt + (size_t)4 * HID_DIM * K_CAT;   // 512*1024
  unsigned short* wsH = wsFc + (size_t)OUT_DIM * HID_DIM;      // 16384*1024
  // total ws: ~93 MB

  prep_cast_kernel<<<dim3(12544), dim3(256), 0, stream>>>(x, h, fcw, wsA, wsFc);
  pack_w_kernel<<<dim3(32, 48, 4), dim3(256), 0, stream>>>(W0, W1, W2, W3, U0, U1,
                                                           U2, U3, wsWt);
  lstm_gates_kernel<<<dim3(128, 16), dim3(256), 0, stream>>>(
      wsA, wsWt, c, b0, b1, b2, b3, h_new, c_new, wsH);
  fc_kernel<<<dim3(128, 4), dim3(256), 0, stream>>>(wsH, wsFc, fcb, out);
}